// Round 2
// baseline (449.445 us; speedup 1.0000x reference)
//
#include <hip/hip_runtime.h>

// SmoothnessConstraint: out[b,0,:]=x[b,0,:]; out[b,t,:]=out[b,t-1,:]+clip(diff,-0.5,0.5)
// B=4096, T=256, A=64 fp32.
//
// R7 (= R6 structure, de-risked): chunked double-buffered streaming pipeline.
//  - Block = one b, 256 threads. T split into 4 chunks of 64 rows (16 KB each),
//    double-buffered: LDS ~37 KB -> 4 blocks/CU = 16 waves/CU.
//  - Staging via global_load_lds width=16 (linear LDS dest = wave-uniform base +
//    lane*16): no VGPR round trip, no ds_write phase.
//  - NO __syncthreads in the main loop (its vmcnt(0) drain was the structural
//    stall). Barriers are __builtin_amdgcn_s_barrier() (convergent-marked,
//    m201-proven) preceded by the minimal asm waitcnt:
//      * iter-top: COUNTED s_waitcnt vmcnt(4). Per-wave VMEM queue (gfx9
//        unified vmcnt, stores count): [stores_{c-2}<=4, loads_c 4,
//        stores_{c-1} 4]; vmcnt(4) retires all but the newest 4 => the
//        chunk-c DMA loads have landed. Prefetch loads stay in flight
//        across B1/B2/store-phase — never drained to 0 in the loop.
//      * B1/B2: s_waitcnt lgkmcnt(0) only (LDS visibility).
//  - Seg-offset sum: fully-unrolled predicated 15-step sum (independent
//    broadcast LDS reads) instead of a serial dependent ds_read chain.
//
// Buffer-reuse safety: DMA for chunk c+1 targets buf[(c+1)&1]; its last
// readers completed their ds_reads before their own lgkmcnt(0) at B1 of
// iter c, and the DMA issues only after all threads pass that barrier.
// carry[] is parity-double-buffered (write slot (c+1)&1 post-B1 of c, read
// slot c&1 post-B1 of c). rawprev write (post-B1 of c) vs read (pre-B1 of
// c+1) is separated by B2 + iter-top barriers.

typedef float v4f __attribute__((ext_vector_type(4)));

__device__ __forceinline__ float clip05(float d) {
    return fminf(fmaxf(d, -0.5f), 0.5f);
}

__device__ __forceinline__ v4f clipdiff(v4f a, v4f b) {   // clip(a - b, +-0.5)
    v4f r;
    r.x = clip05(a.x - b.x);
    r.y = clip05(a.y - b.y);
    r.z = clip05(a.z - b.z);
    r.w = clip05(a.w - b.w);
    return r;
}

__device__ __forceinline__ void ldst16(const v4f* g, v4f* l) {
    __builtin_amdgcn_global_load_lds(
        (const __attribute__((address_space(1))) void*)g,
        (__attribute__((address_space(3))) void*)l,
        16, 0, 0);
}

__global__ __launch_bounds__(256, 4) void smooth_scan(
    const float* __restrict__ in, float* __restrict__ out) {
    constexpr int A4  = 16;           // float4 per timestep row
    constexpr int CV  = 64 * A4;      // 1024 v4f per chunk (16 KB)
    constexpr int NCH = 4;            // chunks per b (T=256)

    __shared__ v4f buf[2][CV];        // 32 KB double buffer
    __shared__ v4f tot[16][A4];       // per-seg clipped-diff totals (4 KB)
    __shared__ v4f carry[2][A4];      // running output at chunk boundary
    __shared__ v4f rawprev[A4];       // raw input at last row of prev chunk

    const int tid = threadIdx.x;
    const int a4  = tid & 15;
    const int seg = tid >> 4;         // 0..15, 4 rows each within a chunk
    const size_t base = (size_t)blockIdx.x * (NCH * CV);
    const v4f* __restrict__ ip = (const v4f*)in + base;
    v4f*       __restrict__ op = (v4f*)out + base;

    // prologue: stage chunk 0 into buf[0]; full drain once
#pragma unroll
    for (int j = 0; j < 4; ++j)
        ldst16(ip + tid + 256 * j, &buf[0][tid + 256 * j]);
    asm volatile("s_waitcnt vmcnt(0)" ::: "memory");
    __builtin_amdgcn_s_barrier();

#pragma unroll
    for (int c = 0; c < NCH; ++c) {
        v4f* bp = buf[c & 1];

        // iter-top: chunk c's DMA landed (only newest 4 stores may remain)
        if (c > 0) {
            asm volatile("s_waitcnt vmcnt(4)" ::: "memory");
            __builtin_amdgcn_s_barrier();
        }

        // part 1: column clipped-diff prefix over this thread's 4 rows.
        // All raw reads happen before B1; finals overwrite only after B1.
        const v4f first = bp[a4];                        // raw x[b,0,:] (c==0)
        v4f prev = (seg == 0) ? ((c == 0) ? first : rawprev[a4])
                              : bp[(seg * 4 - 1) * A4 + a4];
        v4f runs[4];
        v4f run = (v4f){0.f, 0.f, 0.f, 0.f};
        v4f cur = prev;
#pragma unroll
        for (int i = 0; i < 4; ++i) {
            cur = bp[(seg * 4 + i) * A4 + a4];
            run += clipdiff(cur, prev);
            prev = cur;
            runs[i] = run;
        }
        tot[seg][a4] = run;

        // B1: tot visible; all raw boundary reads complete. LDS-only barrier.
        asm volatile("s_waitcnt lgkmcnt(0)" ::: "memory");
        __builtin_amdgcn_s_barrier();

        // prefetch chunk c+1 (async; stays in flight across B2 + stores)
        if (c + 1 < NCH) {
            v4f* nb = buf[(c + 1) & 1];
            const v4f* np = ip + (c + 1) * CV;
#pragma unroll
            for (int j = 0; j < 4; ++j)
                ldst16(np + tid + 256 * j, &nb[tid + 256 * j]);
        }

        // part 2: segment offset = carry + totals of earlier segments.
        // Fixed-trip predicated sum: 15 independent broadcast reads, pipelined.
        v4f off = (c == 0) ? first : carry[c & 1][a4];
#pragma unroll
        for (int s = 0; s < 15; ++s) {
            const v4f tv = tot[s][a4];
            if (s < seg) off += tv;
        }
        // in-place finals for this thread's column
#pragma unroll
        for (int i = 0; i < 4; ++i)
            bp[(seg * 4 + i) * A4 + a4] = off + runs[i];
        if (seg == 15) {
            carry[(c + 1) & 1][a4] = off + runs[3];      // out at last row
            rawprev[a4] = cur;                           // raw last row
        }

        // B2: finals visible. LDS-only barrier — prefetch NOT drained.
        asm volatile("s_waitcnt lgkmcnt(0)" ::: "memory");
        __builtin_amdgcn_s_barrier();

        // coalesced nt stores of chunk c (1 KB contiguous per wave-instruction)
#pragma unroll
        for (int j = 0; j < 4; ++j) {
            const int f = tid + 256 * j;
            __builtin_nontemporal_store(bp[f], op + c * CV + f);
        }
    }
}

extern "C" void kernel_launch(void* const* d_in, const int* in_sizes, int n_in,
                              void* d_out, int out_size, void* d_ws, size_t ws_size,
                              hipStream_t stream) {
    const float* in = (const float*)d_in[0];
    float* out = (float*)d_out;

    constexpr int B = 4096;
    smooth_scan<<<B, 256, 0, stream>>>(in, out);
}

// Round 3
// 441.730 us; speedup vs baseline: 1.0175x; 1.0175x over previous
//
#include <hip/hip_runtime.h>

// SmoothnessConstraint: out[b,0,:]=x[b,0,:]; out[b,t,:]=out[b,t-1,:]+clip(diff,-0.5,0.5)
// B=4096, T=256, A=64 fp32.
//
// R8: wave-per-b shuffle scan. ZERO LDS, ZERO barriers, zero phase structure.
//
// Post-mortem of R5-R7: every LDS-staged variant (coalesced or not, pipelined
// or not) lands at ~4.2 TB/s. R5 already had perfect 1KB-contiguous access, so
// contiguity was never the limiter; the barrier-gated phase alternation was
// (blocks convoy at __syncthreads; memory pipe idles during compute phases).
// R7's global_load_lds pipeline made it worse: the compiler models the DMA as
// VMEM-writing-LDS and inserts vmcnt(0) before every dependent ds_read,
// draining the prefetch -> fully serial loop.
//
// R8 removes the LDS transpose entirely:
//  - wave = one b. Lane l = (tsub = l>>4, a4 = l&15) covers timesteps
//    t0+tsub, float4-column a4. One wave-instruction = 64 lanes x 16 B =
//    exactly one ALIGNED 1 KB contiguous block (the proven 6.3 TB/s copy
//    regime), both for loads and stores.
//  - Scan over the 4 in-flight timesteps: clip diffs (xprev from
//    shfl_up(v,16); tsub==0 takes the carried raw row), then a 2-level
//    masked Hillis-Steele prefix over tsub groups, then add the running
//    carry (out[t0-1], broadcast per a4 via bpermute-shfl from lane 48+a4).
//  - Serial dependence across iterations is only the carry broadcast:
//    ~50 cy x 64 iters ~ 3K cy/wave, vs ~200K cy/wave of BW budget (60x
//    hidden). Loads are address-independent -> 1-deep explicit prefetch
//    keeps HBM busy (per-iter budget ~3.2K cy >> 900 cy HBM latency).
//  - Grid: 1024 blocks x 256 thr = 4096 waves = 16 waves/CU; whole grid
//    resident in one dispatch; ~56 VGPR, LDS 0.

typedef float v4f __attribute__((ext_vector_type(4)));

__device__ __forceinline__ float clip05(float d) {
    return fminf(fmaxf(d, -0.5f), 0.5f);
}

__device__ __forceinline__ v4f clipdiff(v4f a, v4f b) {   // clip(a - b, +-0.5)
    v4f r;
    r.x = clip05(a.x - b.x);
    r.y = clip05(a.y - b.y);
    r.z = clip05(a.z - b.z);
    r.w = clip05(a.w - b.w);
    return r;
}

__device__ __forceinline__ v4f shflv(v4f x, int srcLane) {   // ds_bpermute
    v4f r;
    r.x = __shfl(x.x, srcLane, 64);
    r.y = __shfl(x.y, srcLane, 64);
    r.z = __shfl(x.z, srcLane, 64);
    r.w = __shfl(x.w, srcLane, 64);
    return r;
}

__device__ __forceinline__ v4f shflupv(v4f x, int delta) {
    v4f r;
    r.x = __shfl_up(x.x, delta, 64);
    r.y = __shfl_up(x.y, delta, 64);
    r.z = __shfl_up(x.z, delta, 64);
    r.w = __shfl_up(x.w, delta, 64);
    return r;
}

__global__ __launch_bounds__(256) void smooth_scan(
    const float* __restrict__ in, float* __restrict__ out) {
    constexpr int A4 = 16;            // float4 per timestep row
    constexpr int NV = 256 * A4;      // 4096 v4f per b

    const int tid  = threadIdx.x;
    const int lane = tid & 63;
    const int tsub = lane >> 4;       // 0..3: timestep within the 4-row group
    const int a4   = lane & 15;       // float4 column
    const int b    = blockIdx.x * 4 + (tid >> 6);

    const v4f* __restrict__ ip = (const v4f*)in + (size_t)b * NV;
    v4f*       __restrict__ op = (v4f*)out + (size_t)b * NV;

    // ---- peel t0 = 0 ----
    v4f v  = __builtin_nontemporal_load(ip + lane);        // rows 0..3
    v4f pv = __builtin_nontemporal_load(ip + 64 + lane);   // prefetch rows 4..7

    v4f xp = shflupv(v, 16);                 // row above (tsub>=1)
    v4f cd = (tsub == 0) ? (v4f){0.f, 0.f, 0.f, 0.f} : clipdiff(v, xp);
    // 2-level masked prefix over tsub groups
    v4f s = shflupv(cd, 16);
    if (tsub >= 1) cd += s;
    s = shflupv(cd, 32);
    if (tsub >= 2) cd += s;

    v4f carry = shflv(v, a4);                // x[b,0,a4] broadcast per a4
    v4f o = carry + cd;
    __builtin_nontemporal_store(o, op + lane);
    carry     = shflv(o, 48 + a4);           // out[b,3,a4]
    v4f xlast = shflv(v, 48 + a4);           // raw x[b,3,a4]
    v = pv;

    // ---- steady state: t0 = 4,8,...,252 ----
    for (int t0 = 4; t0 < 256; t0 += 4) {
        v4f nv;
        if (t0 + 4 < 256)                    // prefetch issues before v's use-wait
            nv = __builtin_nontemporal_load(ip + (t0 + 4) * A4 + lane);

        xp = shflupv(v, 16);
        if (tsub == 0) xp = xlast;           // raw row t0-1
        cd = clipdiff(v, xp);
        s = shflupv(cd, 16);
        if (tsub >= 1) cd += s;
        s = shflupv(cd, 32);
        if (tsub >= 2) cd += s;

        o = carry + cd;
        __builtin_nontemporal_store(o, op + t0 * A4 + lane);
        carry = shflv(o, 48 + a4);           // out[b, t0+3, a4]
        xlast = shflv(v, 48 + a4);           // raw x[b, t0+3, a4]
        v = nv;
    }
}

extern "C" void kernel_launch(void* const* d_in, const int* in_sizes, int n_in,
                              void* d_out, int out_size, void* d_ws, size_t ws_size,
                              hipStream_t stream) {
    const float* in = (const float*)d_in[0];
    float* out = (float*)d_out;

    smooth_scan<<<1024, 256, 0, stream>>>(in, out);
}

// Round 4
// 436.214 us; speedup vs baseline: 1.0303x; 1.0126x over previous
//
#include <hip/hip_runtime.h>

// SmoothnessConstraint: out[b,0,:]=x[b,0,:]; out[b,t,:]=out[b,t-1,:]+clip(diff,-0.5,0.5)
// B=4096, T=256, A=64 fp32.
//
// R9: wave-per-b shuffle scan + DEPTH-4 RING PREFETCH + 1-add recurrence.
//
// Post-mortem trail:
//  - R5 (LDS, perfect 1KB coalescing): ~130us kernel -> contiguity not the limiter.
//  - R7 (global_load_lds pipeline): compiler inserts vmcnt(0) before dependent
//    ds_reads -> serialized. Regression.
//  - R8 (shuffle scan, no LDS/barriers, prefetch depth 1): ~150us -> barriers
//    were not the limiter either. Depth-1 prefetch exposes HBM latency every
//    iteration: 1KB/wave outstanding (16KB/CU) with a ~350cy chain between
//    load issues = duty-cycle-limited BW.
//
// R9 fixes:
//  - vb[0..3] register ring: 4 loads (4KB/wave, 64KB/CU) permanently in
//    flight, statically indexed via unroll-4 inner loop (rule #20: no
//    runtime-indexed register arrays). Compiler emits counted vmcnt.
//  - Cross-iteration recurrence reduced to carry += shfl(cd_total): the
//    group total comes from the prefix result cd (lane 48+a4), NOT from o
//    after the store. o = carry+cd and the store are leaves. xlast (raw
//    boundary row) depends only on v. Iterations overlap given loads.
//  - Lane map: lane = tsub*16 + a4; tsub = 4 timesteps, a4 = 16 float4
//    columns. One wave-instruction = 64 lanes x 16B = one aligned 1KB
//    contiguous block (proven 6.3 TB/s regime), loads and stores.
//  - Grid: 1024 blocks x 256 = 4096 waves = 16 waves/CU, whole grid
//    resident; zero LDS, zero barriers.

typedef float v4f __attribute__((ext_vector_type(4)));

__device__ __forceinline__ float clip05(float d) {
    return fminf(fmaxf(d, -0.5f), 0.5f);
}

__device__ __forceinline__ v4f clipdiff(v4f a, v4f b) {   // clip(a - b, +-0.5)
    v4f r;
    r.x = clip05(a.x - b.x);
    r.y = clip05(a.y - b.y);
    r.z = clip05(a.z - b.z);
    r.w = clip05(a.w - b.w);
    return r;
}

__device__ __forceinline__ v4f shflv(v4f x, int srcLane) {   // absolute-lane
    v4f r;
    r.x = __shfl(x.x, srcLane, 64);
    r.y = __shfl(x.y, srcLane, 64);
    r.z = __shfl(x.z, srcLane, 64);
    r.w = __shfl(x.w, srcLane, 64);
    return r;
}

__device__ __forceinline__ v4f shflupv(v4f x, int delta) {
    v4f r;
    r.x = __shfl_up(x.x, delta, 64);
    r.y = __shfl_up(x.y, delta, 64);
    r.z = __shfl_up(x.z, delta, 64);
    r.w = __shfl_up(x.w, delta, 64);
    return r;
}

__global__ __launch_bounds__(256) void smooth_scan(
    const float* __restrict__ in, float* __restrict__ out) {
    constexpr int A4 = 16;            // float4 per timestep row
    constexpr int NV = 256 * A4;      // 4096 v4f per b

    const int tid  = threadIdx.x;
    const int lane = tid & 63;
    const int tsub = lane >> 4;       // 0..3: timestep within the 4-row group
    const int a4   = lane & 15;       // float4 column
    const int b    = blockIdx.x * 4 + (tid >> 6);

    const v4f* __restrict__ ip = (const v4f*)in + (size_t)b * NV;
    v4f*       __restrict__ op = (v4f*)out + (size_t)b * NV;

    // prologue: fill the 4-deep ring (rows 0..15)
    v4f vb0 = __builtin_nontemporal_load(ip + 0 * 64 + lane);
    v4f vb1 = __builtin_nontemporal_load(ip + 1 * 64 + lane);
    v4f vb2 = __builtin_nontemporal_load(ip + 2 * 64 + lane);
    v4f vb3 = __builtin_nontemporal_load(ip + 3 * 64 + lane);

    v4f carry, xlast;

    // ---- it = 0 (t rows 0..3): cd at tsub==0 is clip(v-v)=0 naturally ----
    {
        const v4f v = vb0;
        vb0 = __builtin_nontemporal_load(ip + 4 * 64 + lane);
        v4f cd = clipdiff(v, shflupv(v, 16));        // tsub0: v-v = 0
        v4f s = shflupv(cd, 16); if (tsub >= 1) cd += s;
        s = shflupv(cd, 32);     if (tsub >= 2) cd += s;
        carry = shflv(v, a4);                        // x[b,0,a4] broadcast
        const v4f o = carry + cd;
        __builtin_nontemporal_store(o, op + 0 * 64 + lane);
        carry += shflv(cd, 48 + a4);                 // += group diff total
        xlast  = shflv(v, 48 + a4);                  // raw row 3
    }

    // one scan step for rows 4it..4it+3; slot is the ring register for it&3
    auto step = [&](int it, v4f& slot, bool prefetch) {
        const v4f v = slot;
        if (prefetch)
            slot = __builtin_nontemporal_load(ip + (it + 4) * 64 + lane);
        v4f xp = shflupv(v, 16);
        if (tsub == 0) xp = xlast;                   // raw boundary row
        v4f cd = clipdiff(v, xp);
        v4f s = shflupv(cd, 16); if (tsub >= 1) cd += s;
        s = shflupv(cd, 32);     if (tsub >= 2) cd += s;
        const v4f o = carry + cd;                    // off the critical path
        __builtin_nontemporal_store(o, op + it * 64 + lane);
        carry += shflv(cd, 48 + a4);                 // 1-add recurrence
        xlast  = shflv(v, 48 + a4);                  // depends only on v
    };

    // ---- it = 1..3: finish macro-iter 0 (prefetch rows 20..31) ----
    step(1, vb1, true);
    step(2, vb2, true);
    step(3, vb3, true);

    // ---- steady state: macro-iters 1..14, ring fully hot ----
    for (int mt = 1; mt < 15; ++mt) {
        const int it = mt * 4;
        step(it + 0, vb0, true);
        step(it + 1, vb1, true);
        step(it + 2, vb2, true);
        step(it + 3, vb3, true);
    }

    // ---- tail: macro-iter 15 (rows 240..255), no prefetch ----
    step(60, vb0, false);
    step(61, vb1, false);
    step(62, vb2, false);
    step(63, vb3, false);
}

extern "C" void kernel_launch(void* const* d_in, const int* in_sizes, int n_in,
                              void* d_out, int out_size, void* d_ws, size_t ws_size,
                              hipStream_t stream) {
    const float* in = (const float*)d_in[0];
    float* out = (float*)d_out;

    smooth_scan<<<1024, 256, 0, stream>>>(in, out);
}